// Round 1
// baseline (3522.675 us; speedup 1.0000x reference)
//
#include <hip/hip_runtime.h>
#include <math.h>

// Problem constants
#define HH 1024
#define VV 2048
#define BB 256
#define SS 512
#define NSTEPS 6
#define SOS 129

__device__ __forceinline__ float sigmoidf_(float x) { return 1.0f / (1.0f + expf(-x)); }

// ---------------------------------------------------------------------------
// Generic fp32 GEMM: C[m][n] = act( sum_k A[m][k] * B[n][k] + bias[n] )
// M = 256 fixed (grid.y = 4). Tiles: 64x64, BK=16, 256 threads, 4x4 per thread.
// A may be a virtual concat [A0 | A1] (each K/2 wide); A0 rows may be gathered
// through aidx (embedding lookup). B may be a virtual concat [B0 | B1].
// ---------------------------------------------------------------------------
template<int ACT>  // 0 = none, 1 = tanh
__global__ __launch_bounds__(256) void gemm_kernel(
    const float* __restrict__ A0, const float* __restrict__ A1,
    const int* __restrict__ aidx, int K,
    const float* __restrict__ B0, const float* __restrict__ B1,
    const float* __restrict__ bias,
    float* __restrict__ C, int ldc, int coff)
{
  const int hk = K >> 1;
  __shared__ float As[16][68];  // [k][m], pad 68 -> 272B row stride (16B aligned)
  __shared__ float Bs[16][68];  // [k][n]
  const int t    = threadIdx.x;
  const int row0 = blockIdx.y * 64;
  const int col0 = blockIdx.x * 64;
  const int tx   = t & 15;      // output col group
  const int ty   = t >> 4;      // output row group
  const int lrow = t >> 2;      // staging row 0..63
  const int lk   = (t & 3) << 2;// staging k offset 0,4,8,12

  float acc[4][4] = {};

  const int ar = row0 + lrow;   // batch row this thread stages
  const int br = col0 + lrow;   // B row (output col) this thread stages

  const float* a_lo;
  const float* a_hi = nullptr;
  if (A1) {
    const int r = aidx ? aidx[ar] : ar;
    a_lo = A0 + (size_t)r  * hk;
    a_hi = A1 + (size_t)ar * hk - hk;  // (a_hi + kk) == A1 + ar*hk + (kk-hk)
  } else {
    a_lo = A0 + (size_t)ar * K;
  }
  const float* b_lo;
  const float* b_hi = nullptr;
  if (B1) {
    b_lo = B0 + (size_t)br * hk;
    b_hi = B1 + (size_t)br * hk - hk;
  } else {
    b_lo = B0 + (size_t)br * K;
  }

  for (int k0 = 0; k0 < K; k0 += 16) {
    const int kk = k0 + lk;  // hk is a multiple of 16 -> branch uniform per k0
    const float* asrc = (a_hi && kk >= hk) ? (a_hi + kk) : (a_lo + kk);
    const float* bsrc = (b_hi && kk >= hk) ? (b_hi + kk) : (b_lo + kk);
    const float4 av = *(const float4*)asrc;
    const float4 bv = *(const float4*)bsrc;
    As[lk + 0][lrow] = av.x; As[lk + 1][lrow] = av.y;
    As[lk + 2][lrow] = av.z; As[lk + 3][lrow] = av.w;
    Bs[lk + 0][lrow] = bv.x; Bs[lk + 1][lrow] = bv.y;
    Bs[lk + 2][lrow] = bv.z; Bs[lk + 3][lrow] = bv.w;
    __syncthreads();
#pragma unroll
    for (int k = 0; k < 16; ++k) {
      const float4 a = *(const float4*)&As[k][ty << 2];
      const float4 b = *(const float4*)&Bs[k][tx << 2];
      acc[0][0] += a.x * b.x; acc[0][1] += a.x * b.y; acc[0][2] += a.x * b.z; acc[0][3] += a.x * b.w;
      acc[1][0] += a.y * b.x; acc[1][1] += a.y * b.y; acc[1][2] += a.y * b.z; acc[1][3] += a.y * b.w;
      acc[2][0] += a.z * b.x; acc[2][1] += a.z * b.y; acc[2][2] += a.z * b.z; acc[2][3] += a.z * b.w;
      acc[3][0] += a.w * b.x; acc[3][1] += a.w * b.y; acc[3][2] += a.w * b.z; acc[3][3] += a.w * b.w;
    }
    __syncthreads();
  }

  const int ccol = col0 + (tx << 2);
  const float4 bb = *(const float4*)&bias[ccol];
#pragma unroll
  for (int i = 0; i < 4; ++i) {
    const int r = row0 + (ty << 2) + i;
    float4 v;
    v.x = acc[i][0] + bb.x; v.y = acc[i][1] + bb.y;
    v.z = acc[i][2] + bb.z; v.w = acc[i][3] + bb.w;
    if (ACT == 1) { v.x = tanhf(v.x); v.y = tanhf(v.y); v.z = tanhf(v.z); v.w = tanhf(v.w); }
    *(float4*)&C[(size_t)r * ldc + coff + ccol] = v;
  }
}

// ---------------------------------------------------------------------------
// LSTM elementwise: gates [256][4096] in i,f,g,o order; updates c,h in place.
// ---------------------------------------------------------------------------
__global__ __launch_bounds__(256) void lstm_kernel(const float* __restrict__ gates,
                                                   float* c, float* h)
{
  const int id = blockIdx.x * 256 + threadIdx.x;  // 0..262143
  const int b = id >> 10, j = id & 1023;
  const float* g = gates + (size_t)b * 4096;
  const float ig = g[j], fg = g[j + 1024], gg = g[j + 2048], og = g[j + 3072];
  const float cn = sigmoidf_(fg) * c[id] + sigmoidf_(ig) * tanhf(gg);
  const float hn = sigmoidf_(og) * tanhf(cn);
  c[id] = cn;
  h[id] = hn;
}

// ---------------------------------------------------------------------------
// Fused attention: per batch row b, one pass over enc[b] (512x1024) with
// online softmax. Each of 8 waves computes one score (wave-wide dot) per
// chunk; all 512 threads then fold 8 rows into the context accumulator
// (2 cols/thread, held in registers). Scores kept in LDS -> softmax weights
// written at the end (last step's write persists as the weights output).
// ---------------------------------------------------------------------------
__global__ __launch_bounds__(512) void attn_kernel(const float* __restrict__ energy,
                                                   const float* __restrict__ enc,
                                                   float* __restrict__ ctx,
                                                   float* __restrict__ wout)
{
  const int b = blockIdx.x;
  const int t = threadIdx.x, lane = t & 63, wv = t >> 6;
  __shared__ float sc[SS];
  __shared__ float part[8];
  const float* encb = enc + (size_t)b * (SS * HH);
  const float* eb   = energy + (size_t)b * HH;

  float4 er[4];
#pragma unroll
  for (int i = 0; i < 4; ++i) er[i] = ((const float4*)eb)[lane + 64 * i];

  float m = -INFINITY, l = 0.0f;
  float2 cacc = {0.0f, 0.0f};

  for (int s0 = 0; s0 < SS; s0 += 8) {
    const int s = s0 + wv;
    const float4* row = (const float4*)(encb + (size_t)s * HH);
    float p = 0.0f;
#pragma unroll
    for (int i = 0; i < 4; ++i) {
      const float4 e4 = row[lane + 64 * i];
      p += e4.x * er[i].x + e4.y * er[i].y + e4.z * er[i].z + e4.w * er[i].w;
    }
#pragma unroll
    for (int off = 32; off; off >>= 1) p += __shfl_xor(p, off);
    if (lane == 0) { sc[s] = p; part[wv] = p; }
    __syncthreads();

    float pv[8];
    float mx = m;
#pragma unroll
    for (int w = 0; w < 8; ++w) { pv[w] = part[w]; mx = fmaxf(mx, pv[w]); }
    const float alpha = expf(m - mx);  // expf(-inf)=0 on first chunk
    float esum = 0.0f;
    float2 add = {0.0f, 0.0f};
#pragma unroll
    for (int w = 0; w < 8; ++w) {
      const float e = expf(pv[w] - mx);
      esum += e;
      const float2 v = ((const float2*)(encb + (size_t)(s0 + w) * HH))[t];
      add.x += e * v.x; add.y += e * v.y;
    }
    l = l * alpha + esum;
    cacc.x = cacc.x * alpha + add.x;
    cacc.y = cacc.y * alpha + add.y;
    m = mx;
    __syncthreads();
  }

  const float inv = 1.0f / l;
  float2 o; o.x = cacc.x * inv; o.y = cacc.y * inv;
  ((float2*)(ctx + (size_t)b * HH))[t] = o;
  wout[(size_t)b * SS + t] = expf(sc[t] - m) * inv;  // t in [0,512)
}

// ---------------------------------------------------------------------------
// Greedy argmax over V=2048 logits per row; first-index tie-break (matches
// jnp.argmax). Deterministic tree reduction.
// ---------------------------------------------------------------------------
__global__ __launch_bounds__(256) void argmax_kernel(const float* __restrict__ logits,
                                                     int ldl, int coff,
                                                     int* __restrict__ inp)
{
  const int b = blockIdx.x, t = threadIdx.x;
  const float* row = logits + (size_t)b * ldl + coff;
  float best = -INFINITY; int bi = 0;
  for (int j = t; j < VV; j += 256) {      // ascending per-thread -> first max kept
    const float v = row[j];
    if (v > best) { best = v; bi = j; }
  }
  __shared__ float vs[256];
  __shared__ int   is[256];
  vs[t] = best; is[t] = bi;
  __syncthreads();
  for (int stp = 128; stp; stp >>= 1) {
    if (t < stp) {
      const float v2 = vs[t + stp]; const int i2 = is[t + stp];
      if (v2 > vs[t] || (v2 == vs[t] && i2 < is[t])) { vs[t] = v2; is[t] = i2; }
    }
    __syncthreads();
  }
  if (t == 0) inp[b] = is[0];
}

// ---------------------------------------------------------------------------
// Init: h,c <- h0,c0 (into their d_out slots, used as working state),
// combined LSTM bias, SOS input indices.
// ---------------------------------------------------------------------------
__global__ __launch_bounds__(256) void init_kernel(const float* __restrict__ h0,
                                                   const float* __restrict__ c0,
                                                   float* h, float* c,
                                                   const float* __restrict__ b_ih,
                                                   const float* __restrict__ b_hh,
                                                   float* bihh, int* inp)
{
  const int id = blockIdx.x * 256 + threadIdx.x;
  if (id < BB * HH) { h[id] = h0[id]; c[id] = c0[id]; }
  if (id < 4096) bihh[id] = b_ih[id] + b_hh[id];
  if (id < BB) inp[id] = SOS;
}

extern "C" void kernel_launch(void* const* d_in, const int* in_sizes, int n_in,
                              void* d_out, int out_size, void* d_ws, size_t ws_size,
                              hipStream_t stream)
{
  (void)in_sizes; (void)n_in; (void)out_size; (void)ws_size;
  const float* enc      = (const float*)d_in[0];
  const float* h0       = (const float*)d_in[1];
  const float* c0       = (const float*)d_in[2];
  const float* emb      = (const float*)d_in[3];
  const float* W_ih     = (const float*)d_in[4];
  const float* W_hh     = (const float*)d_in[5];
  const float* b_ih     = (const float*)d_in[6];
  const float* b_hh     = (const float*)d_in[7];
  const float* attn_W   = (const float*)d_in[8];
  const float* attn_b   = (const float*)d_in[9];
  const float* concat_W = (const float*)d_in[10];
  const float* concat_b = (const float*)d_in[11];
  const float* lin_W    = (const float*)d_in[12];
  const float* lin_b    = (const float*)d_in[13];

  float* out = (float*)d_out;
  float* dec = out;                                  // [256][6][2048]
  float* h   = out + (size_t)BB * NSTEPS * VV;       // [256][1024] (final h slot)
  float* c   = h + (size_t)BB * HH;                  // [256][1024] (final c slot)
  float* wts = c + (size_t)BB * HH;                  // [256][512]

  float* ws     = (float*)d_ws;
  float* gates  = ws;                      // 256*4096
  float* energy = gates + (size_t)BB * 4 * HH;   // 256*1024
  float* ctx    = energy + (size_t)BB * HH;      // 256*1024
  float* co     = ctx + (size_t)BB * HH;         // 256*1024
  float* bihh   = co + (size_t)BB * HH;          // 4096
  int*   inp    = (int*)(bihh + 4096);           // 256

  init_kernel<<<1024, 256, 0, stream>>>(h0, c0, h, c, b_ih, b_hh, bihh, inp);

  for (int step = 0; step < NSTEPS; ++step) {
    // gates = [emb[inp] | h] @ [W_ih | W_hh]^T + (b_ih + b_hh)   [256][4096]
    gemm_kernel<0><<<dim3(64, 4), 256, 0, stream>>>(
        emb, h, inp, 2048, W_ih, W_hh, bihh, gates, 4096, 0);
    // c,h update (writes the d_out h/c slots; final step's values persist)
    lstm_kernel<<<1024, 256, 0, stream>>>(gates, c, h);
    // energy = h @ attn_W^T + attn_b   [256][1024]
    gemm_kernel<0><<<dim3(16, 4), 256, 0, stream>>>(
        h, nullptr, nullptr, 1024, attn_W, nullptr, attn_b, energy, 1024, 0);
    // fused scores/softmax/context (single pass over enc); writes weights slot
    attn_kernel<<<BB, 512, 0, stream>>>(energy, enc, ctx, wts);
    // co = tanh([h | ctx] @ concat_W^T + concat_b)   [256][1024]
    gemm_kernel<1><<<dim3(16, 4), 256, 0, stream>>>(
        h, ctx, nullptr, 2048, concat_W, nullptr, concat_b, co, 1024, 0);
    // logits = co @ lin_W^T + lin_b -> d_out[:, step, :]
    gemm_kernel<0><<<dim3(32, 4), 256, 0, stream>>>(
        co, nullptr, nullptr, 1024, lin_W, nullptr, lin_b, dec, NSTEPS * VV, step * VV);
    // greedy next input
    argmax_kernel<<<BB, 256, 0, stream>>>(dec, NSTEPS * VV, step * VV, inp);
  }
}

// Round 2
// 2113.893 us; speedup vs baseline: 1.6664x; 1.6664x over previous
//
#include <hip/hip_runtime.h>
#include <math.h>

// Problem constants
#define HH 1024
#define VV 2048
#define BB 256
#define SS 512
#define NSTEPS 6
#define SOS 129

typedef __attribute__((ext_vector_type(8))) __bf16 bf16x8;
typedef __attribute__((ext_vector_type(4))) __bf16 bf16x4;
typedef __attribute__((ext_vector_type(2))) __bf16 bf16x2;
typedef __attribute__((ext_vector_type(4))) float f32x4;

__device__ __forceinline__ float sigmoidf_(float x) { return 1.0f / (1.0f + expf(-x)); }

// split x into hi+lo bf16 (error ~2^-18 relative)
__device__ __forceinline__ void split1(float x, __bf16& h, __bf16& l) {
  h = (__bf16)x;
  l = (__bf16)(x - (float)h);
}

// ---------------------------------------------------------------------------
// Split-bf16 MFMA GEMM: C[m][n] = act( sum_k A[m][k]*B[n][k] + bias[n] )
// A,B given as pre-split (hi,lo) bf16 arrays, both K-major.
// C = Ah*Bh + Ah*Bl + Al*Bh (fp32 MFMA accumulate).
// Tiles: 64x64, BK=64, 256 threads (4 waves), wave computes 32x32.
// OMODE 0: fp32 C (ldc,coff). OMODE 1: split bf16 out (Ch,Cl,ldco).
// ---------------------------------------------------------------------------
template<int ACT, int OMODE>
__global__ __launch_bounds__(256) void gemm_bf16s(
    const __bf16* __restrict__ Ah_g, const __bf16* __restrict__ Al_g, int lda,
    const __bf16* __restrict__ Bh_g, const __bf16* __restrict__ Bl_g,
    const float* __restrict__ bias, int K,
    float* __restrict__ C, int ldc, int coff,
    __bf16* __restrict__ Ch, __bf16* __restrict__ Cl, int ldco)
{
  __shared__ __align__(16) __bf16 sAh[64 * 64], sAl[64 * 64], sBh[64 * 64], sBl[64 * 64];
  const int t = threadIdx.x;
  const int row0 = blockIdx.y * 64, col0 = blockIdx.x * 64;
  const int lr = t & 63;     // staging row in tile
  const int q  = t >> 6;     // staging k-quarter (16 elems)
  const int ar = row0 + lr, br = col0 + lr;
  const __bf16* pAh = Ah_g + (size_t)ar * lda;
  const __bf16* pAl = Al_g + (size_t)ar * lda;
  const __bf16* pBh = Bh_g + (size_t)br * K;
  const __bf16* pBl = Bl_g + (size_t)br * K;

  const int lane = t & 63;
  const int wv = t >> 6;
  const int wr = (wv >> 1) * 32, wc = (wv & 1) * 32;   // wave quadrant
  const int fr = lane & 15, kb = (lane >> 4) * 8;      // frag row / k-base

  const f32x4 fz = {0.f, 0.f, 0.f, 0.f};
  f32x4 acc[2][2] = {{fz, fz}, {fz, fz}};

  for (int k0 = 0; k0 < K; k0 += 64) {
#pragma unroll
    for (int n = 0; n < 2; ++n) {
      const int e = q * 16 + n * 8;                    // k-offset of 8-elem chunk
      const int sidx = lr * 64 + (e ^ ((lr & 7) << 3)); // XOR swizzle (16B granules)
      *(bf16x8*)&sAh[sidx] = *(const bf16x8*)(pAh + k0 + e);
      *(bf16x8*)&sAl[sidx] = *(const bf16x8*)(pAl + k0 + e);
      *(bf16x8*)&sBh[sidx] = *(const bf16x8*)(pBh + k0 + e);
      *(bf16x8*)&sBl[sidx] = *(const bf16x8*)(pBl + k0 + e);
    }
    __syncthreads();
#pragma unroll
    for (int kc = 0; kc < 2; ++kc) {
      const int e = kc * 32 + kb;
      bf16x8 a_h[2], a_l[2], b_h[2], b_l[2];
#pragma unroll
      for (int i = 0; i < 2; ++i) {
        const int ra = wr + i * 16 + fr;
        const int ia = ra * 64 + (e ^ ((ra & 7) << 3));
        a_h[i] = *(const bf16x8*)&sAh[ia];
        a_l[i] = *(const bf16x8*)&sAl[ia];
        const int rb = wc + i * 16 + fr;
        const int ib = rb * 64 + (e ^ ((rb & 7) << 3));
        b_h[i] = *(const bf16x8*)&sBh[ib];
        b_l[i] = *(const bf16x8*)&sBl[ib];
      }
#pragma unroll
      for (int i = 0; i < 2; ++i)
#pragma unroll
        for (int j = 0; j < 2; ++j)
          acc[i][j] = __builtin_amdgcn_mfma_f32_16x16x32_bf16(a_h[i], b_h[j], acc[i][j], 0, 0, 0);
#pragma unroll
      for (int i = 0; i < 2; ++i)
#pragma unroll
        for (int j = 0; j < 2; ++j)
          acc[i][j] = __builtin_amdgcn_mfma_f32_16x16x32_bf16(a_h[i], b_l[j], acc[i][j], 0, 0, 0);
#pragma unroll
      for (int i = 0; i < 2; ++i)
#pragma unroll
        for (int j = 0; j < 2; ++j)
          acc[i][j] = __builtin_amdgcn_mfma_f32_16x16x32_bf16(a_l[i], b_h[j], acc[i][j], 0, 0, 0);
    }
    __syncthreads();
  }

  // Epilogue. C/D layout: col = lane&15, row = (lane>>4)*4 + reg.
#pragma unroll
  for (int i = 0; i < 2; ++i)
#pragma unroll
    for (int j = 0; j < 2; ++j) {
      const int col = col0 + wc + j * 16 + fr;
      const float bb = bias[col];
#pragma unroll
      for (int r = 0; r < 4; ++r) {
        const int row = row0 + wr + i * 16 + (lane >> 4) * 4 + r;
        float v = acc[i][j][r] + bb;
        if (ACT == 1) v = tanhf(v);
        if (OMODE == 0) {
          C[(size_t)row * ldc + coff + col] = v;
        } else {
          __bf16 vh, vl;
          split1(v, vh, vl);
          Ch[(size_t)row * ldco + col] = vh;
          Cl[(size_t)row * ldco + col] = vl;
        }
      }
    }
}

// ---------------------------------------------------------------------------
// Weight split-conversion: fp32 src [rows][cols] -> (hi,lo) bf16 dst with
// row stride dld and column offset doff (for concatenating W_ih|W_hh).
// ---------------------------------------------------------------------------
__global__ __launch_bounds__(256) void conv_split_kernel(
    const float* __restrict__ src, __bf16* __restrict__ dh, __bf16* __restrict__ dl,
    int cols, int dld, int doff, int n4)
{
  const int idx = blockIdx.x * 256 + threadIdx.x;
  if (idx >= n4) return;
  const int c4 = cols >> 2;
  const int r = idx / c4, cp = (idx - r * c4) << 2;
  const float4 v = *(const float4*)(src + (size_t)r * cols + cp);
  __bf16 h0, l0, h1, l1, h2, l2, h3, l3;
  split1(v.x, h0, l0); split1(v.y, h1, l1); split1(v.z, h2, l2); split1(v.w, h3, l3);
  const size_t o = (size_t)r * dld + doff + cp;
  *(bf16x4*)&dh[o] = bf16x4{h0, h1, h2, h3};
  *(bf16x4*)&dl[o] = bf16x4{l0, l1, l2, l3};
}

// ---------------------------------------------------------------------------
// Embedding gather + split: x = emb[inp[b]] -> xcat[:, 0:1024] (hi,lo)
// ---------------------------------------------------------------------------
__global__ __launch_bounds__(256) void gather_kernel(
    const float* __restrict__ emb, const int* __restrict__ inp,
    __bf16* __restrict__ xh, __bf16* __restrict__ xl)
{
  const int b = blockIdx.x, t = threadIdx.x;
  const float4 v = *(const float4*)(emb + (size_t)inp[b] * HH + t * 4);
  __bf16 h0, l0, h1, l1, h2, l2, h3, l3;
  split1(v.x, h0, l0); split1(v.y, h1, l1); split1(v.z, h2, l2); split1(v.w, h3, l3);
  const size_t o = (size_t)b * 2048 + t * 4;
  *(bf16x4*)&xh[o] = bf16x4{h0, h1, h2, h3};
  *(bf16x4*)&xl[o] = bf16x4{l0, l1, l2, l3};
}

// ---------------------------------------------------------------------------
// LSTM elementwise; also emits h in split form into xcat[:,1024:] (for next
// step's gates GEMM) and hcat[:,0:1024] (for energy/concat GEMMs).
// ---------------------------------------------------------------------------
__global__ __launch_bounds__(256) void lstm_kernel(
    const float* __restrict__ gates, float* c, float* h,
    __bf16* __restrict__ xcat_h, __bf16* __restrict__ xcat_l,
    __bf16* __restrict__ hcat_h, __bf16* __restrict__ hcat_l)
{
  const int id = blockIdx.x * 256 + threadIdx.x;  // 0..262143
  const int b = id >> 10, j = id & 1023;
  const float* g = gates + (size_t)b * 4096;
  const float ig = g[j], fg = g[j + 1024], gg = g[j + 2048], og = g[j + 3072];
  const float cn = sigmoidf_(fg) * c[id] + sigmoidf_(ig) * tanhf(gg);
  const float hn = sigmoidf_(og) * tanhf(cn);
  c[id] = cn;
  h[id] = hn;
  __bf16 hh, hl;
  split1(hn, hh, hl);
  const size_t o = (size_t)b * 2048;
  xcat_h[o + 1024 + j] = hh; xcat_l[o + 1024 + j] = hl;
  hcat_h[o + j] = hh;        hcat_l[o + j] = hl;
}

// ---------------------------------------------------------------------------
// Fused attention (fp32, memory-bound): online softmax over enc rows.
// Emits context in split form into hcat[:,1024:]; writes softmax weights.
// ---------------------------------------------------------------------------
__global__ __launch_bounds__(512) void attn_kernel(
    const float* __restrict__ energy, const float* __restrict__ enc,
    __bf16* __restrict__ hcat_h, __bf16* __restrict__ hcat_l,
    float* __restrict__ wout)
{
  const int b = blockIdx.x;
  const int t = threadIdx.x, lane = t & 63, wv = t >> 6;
  __shared__ float sc[SS];
  __shared__ float part[8];
  const float* encb = enc + (size_t)b * (SS * HH);
  const float* eb   = energy + (size_t)b * HH;

  float4 er[4];
#pragma unroll
  for (int i = 0; i < 4; ++i) er[i] = ((const float4*)eb)[lane + 64 * i];

  float m = -INFINITY, l = 0.0f;
  float2 cacc = {0.0f, 0.0f};

  for (int s0 = 0; s0 < SS; s0 += 8) {
    const int s = s0 + wv;
    const float4* row = (const float4*)(encb + (size_t)s * HH);
    float p = 0.0f;
#pragma unroll
    for (int i = 0; i < 4; ++i) {
      const float4 e4 = row[lane + 64 * i];
      p += e4.x * er[i].x + e4.y * er[i].y + e4.z * er[i].z + e4.w * er[i].w;
    }
#pragma unroll
    for (int off = 32; off; off >>= 1) p += __shfl_xor(p, off);
    if (lane == 0) { sc[s] = p; part[wv] = p; }
    __syncthreads();

    float pv[8];
    float mx = m;
#pragma unroll
    for (int w = 0; w < 8; ++w) { pv[w] = part[w]; mx = fmaxf(mx, pv[w]); }
    const float alpha = expf(m - mx);
    float esum = 0.0f;
    float2 add = {0.0f, 0.0f};
#pragma unroll
    for (int w = 0; w < 8; ++w) {
      const float e = expf(pv[w] - mx);
      esum += e;
      const float2 v = ((const float2*)(encb + (size_t)(s0 + w) * HH))[t];
      add.x += e * v.x; add.y += e * v.y;
    }
    l = l * alpha + esum;
    cacc.x = cacc.x * alpha + add.x;
    cacc.y = cacc.y * alpha + add.y;
    m = mx;
    __syncthreads();
  }

  const float inv = 1.0f / l;
  const float ox = cacc.x * inv, oy = cacc.y * inv;
  __bf16 h0, l0, h1, l1;
  split1(ox, h0, l0); split1(oy, h1, l1);
  const size_t ob = (size_t)b * 2048 + 1024 + 2 * t;
  *(bf16x2*)&hcat_h[ob] = bf16x2{h0, h1};
  *(bf16x2*)&hcat_l[ob] = bf16x2{l0, l1};
  wout[(size_t)b * SS + t] = expf(sc[t] - m) * inv;
}

// ---------------------------------------------------------------------------
// Greedy argmax over V=2048 logits; first-index tie-break (matches jnp.argmax).
// ---------------------------------------------------------------------------
__global__ __launch_bounds__(256) void argmax_kernel(
    const float* __restrict__ logits, int ldl, int coff, int* __restrict__ inp)
{
  const int b = blockIdx.x, t = threadIdx.x;
  const float* row = logits + (size_t)b * ldl + coff;
  float best = -INFINITY; int bi = 0;
  for (int j = t; j < VV; j += 256) {
    const float v = row[j];
    if (v > best) { best = v; bi = j; }
  }
  __shared__ float vs[256];
  __shared__ int   is[256];
  vs[t] = best; is[t] = bi;
  __syncthreads();
  for (int stp = 128; stp; stp >>= 1) {
    if (t < stp) {
      const float v2 = vs[t + stp]; const int i2 = is[t + stp];
      if (v2 > vs[t] || (v2 == vs[t] && i2 < is[t])) { vs[t] = v2; is[t] = i2; }
    }
    __syncthreads();
  }
  if (t == 0) inp[b] = is[0];
}

// ---------------------------------------------------------------------------
// Init: h,c <- h0,c0 (into d_out slots), h split into xcat/hcat, combined
// LSTM bias, SOS indices.
// ---------------------------------------------------------------------------
__global__ __launch_bounds__(256) void init_kernel(
    const float* __restrict__ h0, const float* __restrict__ c0,
    float* h, float* c,
    const float* __restrict__ b_ih, const float* __restrict__ b_hh,
    float* bihh, int* inp,
    __bf16* __restrict__ xcat_h, __bf16* __restrict__ xcat_l,
    __bf16* __restrict__ hcat_h, __bf16* __restrict__ hcat_l)
{
  const int id = blockIdx.x * 256 + threadIdx.x;
  if (id < BB * HH) {
    const float hv = h0[id];
    h[id] = hv;
    c[id] = c0[id];
    __bf16 hh, hl;
    split1(hv, hh, hl);
    const int b = id >> 10, j = id & 1023;
    const size_t o = (size_t)b * 2048;
    xcat_h[o + 1024 + j] = hh; xcat_l[o + 1024 + j] = hl;
    hcat_h[o + j] = hh;        hcat_l[o + j] = hl;
  }
  if (id < 4096) bihh[id] = b_ih[id] + b_hh[id];
  if (id < BB) inp[id] = SOS;
}

extern "C" void kernel_launch(void* const* d_in, const int* in_sizes, int n_in,
                              void* d_out, int out_size, void* d_ws, size_t ws_size,
                              hipStream_t stream)
{
  (void)in_sizes; (void)n_in; (void)out_size; (void)ws_size;
  const float* enc      = (const float*)d_in[0];
  const float* h0       = (const float*)d_in[1];
  const float* c0       = (const float*)d_in[2];
  const float* emb      = (const float*)d_in[3];
  const float* W_ih     = (const float*)d_in[4];
  const float* W_hh     = (const float*)d_in[5];
  const float* b_ih     = (const float*)d_in[6];
  const float* b_hh     = (const float*)d_in[7];
  const float* attn_W   = (const float*)d_in[8];
  const float* attn_b   = (const float*)d_in[9];
  const float* concat_W = (const float*)d_in[10];
  const float* concat_b = (const float*)d_in[11];
  const float* lin_W    = (const float*)d_in[12];
  const float* lin_b    = (const float*)d_in[13];

  float* out = (float*)d_out;
  float* dec = out;                                  // [256][6][2048]
  float* h   = out + (size_t)BB * NSTEPS * VV;       // [256][1024]
  float* c   = h + (size_t)BB * HH;                  // [256][1024]
  float* wts = c + (size_t)BB * HH;                  // [256][512]

  // workspace carve-up
  char* w = (char*)d_ws;
  auto alloc = [&](size_t bytes) { char* p = w; w += (bytes + 255) & ~255ull; return p; };
  float*  gates    = (float*)alloc((size_t)BB * 4096 * 4);
  float*  energy   = (float*)alloc((size_t)BB * HH * 4);
  float*  bihh     = (float*)alloc(4096 * 4);
  int*    inp      = (int*)alloc(BB * 4);
  __bf16* Wcat_h   = (__bf16*)alloc((size_t)4096 * 2048 * 2);
  __bf16* Wcat_l   = (__bf16*)alloc((size_t)4096 * 2048 * 2);
  __bf16* attnW_h  = (__bf16*)alloc((size_t)1024 * 1024 * 2);
  __bf16* attnW_l  = (__bf16*)alloc((size_t)1024 * 1024 * 2);
  __bf16* catW_h   = (__bf16*)alloc((size_t)1024 * 2048 * 2);
  __bf16* catW_l   = (__bf16*)alloc((size_t)1024 * 2048 * 2);
  __bf16* linW_h   = (__bf16*)alloc((size_t)2048 * 1024 * 2);
  __bf16* linW_l   = (__bf16*)alloc((size_t)2048 * 1024 * 2);
  __bf16* xcat_h   = (__bf16*)alloc((size_t)BB * 2048 * 2);
  __bf16* xcat_l   = (__bf16*)alloc((size_t)BB * 2048 * 2);
  __bf16* hcat_h   = (__bf16*)alloc((size_t)BB * 2048 * 2);
  __bf16* hcat_l   = (__bf16*)alloc((size_t)BB * 2048 * 2);
  __bf16* co_h     = (__bf16*)alloc((size_t)BB * 1024 * 2);
  __bf16* co_l     = (__bf16*)alloc((size_t)BB * 1024 * 2);

  // one-time weight conversions (fp32 -> hi/lo bf16)
  conv_split_kernel<<<4096, 256, 0, stream>>>(W_ih, Wcat_h, Wcat_l, 1024, 2048, 0, 4096 * 256);
  conv_split_kernel<<<4096, 256, 0, stream>>>(W_hh, Wcat_h, Wcat_l, 1024, 2048, 1024, 4096 * 256);
  conv_split_kernel<<<1024, 256, 0, stream>>>(attn_W, attnW_h, attnW_l, 1024, 1024, 0, 1024 * 256);
  conv_split_kernel<<<2048, 256, 0, stream>>>(concat_W, catW_h, catW_l, 2048, 2048, 0, 1024 * 512);
  conv_split_kernel<<<2048, 256, 0, stream>>>(lin_W, linW_h, linW_l, 1024, 1024, 0, 2048 * 256);

  init_kernel<<<1024, 256, 0, stream>>>(h0, c0, h, c, b_ih, b_hh, bihh, inp,
                                        xcat_h, xcat_l, hcat_h, hcat_l);

  for (int step = 0; step < NSTEPS; ++step) {
    // x = emb[inp] -> xcat[:, :1024]
    gather_kernel<<<BB, 256, 0, stream>>>(emb, inp, xcat_h, xcat_l);
    // gates = [x|h] @ [W_ih|W_hh]^T + bihh   [256][4096]
    gemm_bf16s<0, 0><<<dim3(64, 4), 256, 0, stream>>>(
        xcat_h, xcat_l, 2048, Wcat_h, Wcat_l, bihh, 2048,
        gates, 4096, 0, nullptr, nullptr, 0);
    lstm_kernel<<<1024, 256, 0, stream>>>(gates, c, h, xcat_h, xcat_l, hcat_h, hcat_l);
    // energy = h @ attn_W^T + attn_b   [256][1024]
    gemm_bf16s<0, 0><<<dim3(16, 4), 256, 0, stream>>>(
        hcat_h, hcat_l, 2048, attnW_h, attnW_l, attn_b, 1024,
        energy, 1024, 0, nullptr, nullptr, 0);
    // fused scores/softmax/context; ctx -> hcat[:,1024:], weights -> wts
    attn_kernel<<<BB, 512, 0, stream>>>(energy, enc, hcat_h, hcat_l, wts);
    // co = tanh([h|ctx] @ concat_W^T + concat_b) -> split (co_h, co_l)
    gemm_bf16s<1, 1><<<dim3(16, 4), 256, 0, stream>>>(
        hcat_h, hcat_l, 2048, catW_h, catW_l, concat_b, 2048,
        nullptr, 0, 0, co_h, co_l, 1024);
    // logits = co @ lin_W^T + lin_b -> d_out[:, step, :]
    gemm_bf16s<0, 0><<<dim3(32, 4), 256, 0, stream>>>(
        co_h, co_l, 1024, linW_h, linW_l, lin_b, 1024,
        dec, NSTEPS * VV, step * VV, nullptr, nullptr, 0);
    argmax_kernel<<<BB, 256, 0, stream>>>(dec, NSTEPS * VV, step * VV, inp);
  }
}

// Round 3
// 1585.426 us; speedup vs baseline: 2.2219x; 1.3333x over previous
//
#include <hip/hip_runtime.h>
#include <math.h>

#define HH 1024
#define VV 2048
#define BB 256
#define SS 512
#define NSTEPS 6
#define SOS 129

typedef __attribute__((ext_vector_type(8))) __bf16 bf16x8;
typedef __attribute__((ext_vector_type(4))) __bf16 bf16x4;
typedef __attribute__((ext_vector_type(2))) __bf16 bf16x2;
typedef __attribute__((ext_vector_type(4))) float f32x4;

__device__ __forceinline__ float sigmoidf_(float x) { return 1.0f / (1.0f + expf(-x)); }

__device__ __forceinline__ void split1(float x, __bf16& h, __bf16& l) {
  h = (__bf16)x;
  l = (__bf16)(x - (float)h);
}

// async global->LDS, 16B per lane; LDS dest must be wave-uniform base.
__device__ __forceinline__ void gll16(const __bf16* src, __bf16* ldst) {
  __builtin_amdgcn_global_load_lds(
      (const __attribute__((address_space(1))) unsigned*)(const void*)src,
      (__attribute__((address_space(3))) unsigned*)(void*)ldst, 16, 0, 0);
}

// ---------------------------------------------------------------------------
// Split-bf16 MFMA GEMM, double-buffered, global_load_lds staging.
// C[m][n] = act( sum_k A[m][k]*B[n][k] + bias[n] ),  C = Ah*Bh + Ah*Bl + Al*Bh.
// Tile 64x64, BK=64, 256 threads (4 waves), wave-tile 32x32.
// LDS layout per buffer: 4 arrays (Ah,Al,Bh,Bl) of [64 rows][64 elems] bf16,
// row slot s (8 elems) holds global k-chunk (s ^ (row&7))  [XOR swizzle,
// applied on the GLOBAL source address; LDS writes stay linear].
// AMODE 0: A = Ah/Al with row stride lda.
// AMODE 1: A = [emb[aidx[r]] | hcat[r][0:1024]]  (gates GEMM, K=2048).
// OMODE 0: fp32 C (ldc,coff).  OMODE 1: split bf16 out (Ch,Cl,ldco).
// ---------------------------------------------------------------------------
template<int ACT, int OMODE, int AMODE>
__global__ __launch_bounds__(256) void gemm3(
    const __bf16* __restrict__ Ah, const __bf16* __restrict__ Al, int lda,
    const __bf16* __restrict__ A1h, const __bf16* __restrict__ A1l,
    const int* __restrict__ aidx,
    const __bf16* __restrict__ Bh, const __bf16* __restrict__ Bl,
    const float* __restrict__ bias, int K,
    float* __restrict__ C, int ldc, int coff,
    __bf16* __restrict__ Ch, __bf16* __restrict__ Cl, int ldco)
{
  __shared__ __align__(16) __bf16 lds[2][4][64 * 64];  // 64 KB
  const int t = threadIdx.x, lane = t & 63, wv = t >> 6;
  const int row0 = blockIdx.y * 64, col0 = blockIdx.x * 64;

  // staging geometry: per (hf in 0..1) this lane writes tile row tr, slot sslot
  const int sslot = lane & 7;
  const int srw   = lane >> 3;  // 0..7
  int sw[2];
  const __bf16 *arh[2], *arl[2], *a1h[2], *a1l[2], *brh[2], *brl[2];
#pragma unroll
  for (int hf = 0; hf < 2; ++hf) {
    const int tr = wv * 16 + hf * 8 + srw;
    sw[hf] = (sslot ^ (tr & 7)) << 3;       // element offset of swizzled chunk
    const int ar = row0 + tr;
    if (AMODE == 1) {
      const int r = aidx[ar];
      arh[hf] = Ah + (size_t)r * HH;        // emb_h row
      arl[hf] = Al + (size_t)r * HH;
      a1h[hf] = A1h + (size_t)ar * 2048;    // hcat row (h part, cols 0..1023)
      a1l[hf] = A1l + (size_t)ar * 2048;
    } else {
      arh[hf] = Ah + (size_t)ar * lda;
      arl[hf] = Al + (size_t)ar * lda;
    }
    const int br = col0 + tr;
    brh[hf] = Bh + (size_t)br * K;
    brl[hf] = Bl + (size_t)br * K;
  }

  const int wr = (wv >> 1) * 32, wc = (wv & 1) * 32;
  const int fr = lane & 15, kb = (lane >> 4) * 8;

  const f32x4 fz = {0.f, 0.f, 0.f, 0.f};
  f32x4 acc[2][2] = {{fz, fz}, {fz, fz}};

  const int nt = K >> 6;

  auto stage = [&](int tk, int bi) {
    const int k0 = tk << 6;
#pragma unroll
    for (int hf = 0; hf < 2; ++hf) {
      const int rb = (wv * 16 + hf * 8) * 64;          // wave-uniform LDS base
      const __bf16 *sa_h, *sa_l;
      if (AMODE == 1 && k0 >= HH) {
        sa_h = a1h[hf] + (k0 - HH) + sw[hf];
        sa_l = a1l[hf] + (k0 - HH) + sw[hf];
      } else {
        sa_h = arh[hf] + k0 + sw[hf];
        sa_l = arl[hf] + k0 + sw[hf];
      }
      gll16(sa_h, &lds[bi][0][rb]);
      gll16(sa_l, &lds[bi][1][rb]);
      gll16(brh[hf] + k0 + sw[hf], &lds[bi][2][rb]);
      gll16(brl[hf] + k0 + sw[hf], &lds[bi][3][rb]);
    }
  };

  auto compute = [&](int bi) {
#pragma unroll
    for (int kc = 0; kc < 2; ++kc) {
      const int e = kc * 32 + kb;
      bf16x8 a_h[2], a_l[2], b_h[2], b_l[2];
#pragma unroll
      for (int i = 0; i < 2; ++i) {
        const int ra = wr + i * 16 + fr;
        const int ia = ra * 64 + (e ^ ((ra & 7) << 3));
        a_h[i] = *(const bf16x8*)&lds[bi][0][ia];
        a_l[i] = *(const bf16x8*)&lds[bi][1][ia];
        const int rb2 = wc + i * 16 + fr;
        const int ib = rb2 * 64 + (e ^ ((rb2 & 7) << 3));
        b_h[i] = *(const bf16x8*)&lds[bi][2][ib];
        b_l[i] = *(const bf16x8*)&lds[bi][3][ib];
      }
#pragma unroll
      for (int i = 0; i < 2; ++i)
#pragma unroll
        for (int j = 0; j < 2; ++j)
          acc[i][j] = __builtin_amdgcn_mfma_f32_16x16x32_bf16(a_h[i], b_h[j], acc[i][j], 0, 0, 0);
#pragma unroll
      for (int i = 0; i < 2; ++i)
#pragma unroll
        for (int j = 0; j < 2; ++j)
          acc[i][j] = __builtin_amdgcn_mfma_f32_16x16x32_bf16(a_h[i], b_l[j], acc[i][j], 0, 0, 0);
#pragma unroll
      for (int i = 0; i < 2; ++i)
#pragma unroll
        for (int j = 0; j < 2; ++j)
          acc[i][j] = __builtin_amdgcn_mfma_f32_16x16x32_bf16(a_l[i], b_h[j], acc[i][j], 0, 0, 0);
    }
  };

  stage(0, 0);
  __syncthreads();
  int cur = 0;
  for (int tk = 0; tk < nt; ++tk) {
    if (tk + 1 < nt) stage(tk + 1, cur ^ 1);  // prefetch before compute
    compute(cur);
    __syncthreads();                          // drains prefetch after compute
    cur ^= 1;
  }

  // Epilogue. C/D layout (validated R2): col = lane&15, row = (lane>>4)*4 + reg.
#pragma unroll
  for (int i = 0; i < 2; ++i)
#pragma unroll
    for (int j = 0; j < 2; ++j) {
      const int col = col0 + wc + j * 16 + fr;
      const float bb = bias[col];
#pragma unroll
      for (int r = 0; r < 4; ++r) {
        const int row = row0 + wr + i * 16 + (lane >> 4) * 4 + r;
        float v = acc[i][j][r] + bb;
        if (ACT == 1) v = tanhf(v);
        if (OMODE == 0) {
          C[(size_t)row * ldc + coff + col] = v;
        } else {
          __bf16 vh, vl;
          split1(v, vh, vl);
          Ch[(size_t)row * ldco + col] = vh;
          Cl[(size_t)row * ldco + col] = vl;
        }
      }
    }
}

// ---------------------------------------------------------------------------
// One-shot conversion of all fp32 weights (+ embedding) to split hi/lo bf16.
// Index space: 4-float groups over concatenated regions.
// ---------------------------------------------------------------------------
__global__ __launch_bounds__(256) void conv_all(
    const float* __restrict__ W_ih, const float* __restrict__ W_hh,
    const float* __restrict__ attn_W, const float* __restrict__ concat_W,
    const float* __restrict__ lin_W, const float* __restrict__ emb,
    __bf16* __restrict__ Wcat_h, __bf16* __restrict__ Wcat_l,
    __bf16* __restrict__ attnW_h, __bf16* __restrict__ attnW_l,
    __bf16* __restrict__ catW_h, __bf16* __restrict__ catW_l,
    __bf16* __restrict__ linW_h, __bf16* __restrict__ linW_l,
    __bf16* __restrict__ emb_h, __bf16* __restrict__ emb_l)
{
  const int i = blockIdx.x * 256 + threadIdx.x;  // 4-float group id
  const float* s;
  __bf16 *dh, *dl;
  size_t so, dofs;
  if (i < 2097152) {                       // W_ih | W_hh -> Wcat (remapped)
    const int ii = i & 1048575;
    const int r = ii >> 8, cp = (ii & 255) << 2;
    s = (i < 1048576) ? W_ih : W_hh;
    so = (size_t)r * 1024 + cp;
    dh = Wcat_h; dl = Wcat_l;
    dofs = (size_t)r * 2048 + ((i < 1048576) ? 0 : 1024) + cp;
  } else if (i < 2359296) {                // attn_W (contiguous)
    const size_t ii = (size_t)(i - 2097152) << 2;
    s = attn_W; so = ii; dh = attnW_h; dl = attnW_l; dofs = ii;
  } else if (i < 2883584) {                // concat_W
    const size_t ii = (size_t)(i - 2359296) << 2;
    s = concat_W; so = ii; dh = catW_h; dl = catW_l; dofs = ii;
  } else if (i < 3407872) {                // lin_W
    const size_t ii = (size_t)(i - 2883584) << 2;
    s = lin_W; so = ii; dh = linW_h; dl = linW_l; dofs = ii;
  } else {                                 // embedding
    const size_t ii = (size_t)(i - 3407872) << 2;
    s = emb; so = ii; dh = emb_h; dl = emb_l; dofs = ii;
  }
  const float4 v = *(const float4*)(s + so);
  __bf16 h0, l0, h1, l1, h2, l2, h3, l3;
  split1(v.x, h0, l0); split1(v.y, h1, l1); split1(v.z, h2, l2); split1(v.w, h3, l3);
  *(bf16x4*)&dh[dofs] = bf16x4{h0, h1, h2, h3};
  *(bf16x4*)&dl[dofs] = bf16x4{l0, l1, l2, l3};
}

// ---------------------------------------------------------------------------
// LSTM elementwise; emits h split into hcat[:,0:1024].
// ---------------------------------------------------------------------------
__global__ __launch_bounds__(256) void lstm_kernel(
    const float* __restrict__ gates, float* c, float* h,
    __bf16* __restrict__ hcat_h, __bf16* __restrict__ hcat_l)
{
  const int id = blockIdx.x * 256 + threadIdx.x;
  const int b = id >> 10, j = id & 1023;
  const float* g = gates + (size_t)b * 4096;
  const float ig = g[j], fg = g[j + 1024], gg = g[j + 2048], og = g[j + 3072];
  const float cn = sigmoidf_(fg) * c[id] + sigmoidf_(ig) * tanhf(gg);
  const float hn = sigmoidf_(og) * tanhf(cn);
  c[id] = cn;
  h[id] = hn;
  __bf16 hh, hl;
  split1(hn, hh, hl);
  hcat_h[(size_t)b * 2048 + j] = hh;
  hcat_l[(size_t)b * 2048 + j] = hl;
}

// ---------------------------------------------------------------------------
// Attention part: WG (b, half) processes 256 enc rows with online softmax.
// Writes partial (m,l), partial context accumulator, raw scores.
// 512 WGs -> 2 WGs/CU for latency hiding.
// ---------------------------------------------------------------------------
__global__ __launch_bounds__(512) void attn_part(
    const float* __restrict__ energy, const float* __restrict__ enc,
    float* __restrict__ pml, float* __restrict__ pcacc, float* __restrict__ scb)
{
  const int b = blockIdx.x >> 1, half = blockIdx.x & 1;
  const int base = half * 256;
  const int t = threadIdx.x, lane = t & 63, wv = t >> 6;
  __shared__ float part[8];
  const float* encb = enc + (size_t)b * (SS * HH);
  const float* eb   = energy + (size_t)b * HH;

  float4 er[4];
#pragma unroll
  for (int i = 0; i < 4; ++i) er[i] = ((const float4*)eb)[lane + 64 * i];

  float m = -INFINITY, l = 0.0f;
  float2 cacc = {0.0f, 0.0f};

  // register prefetch pipeline for this wave's score row
  float4 r4[4];
  {
    const float4* row = (const float4*)(encb + (size_t)(base + wv) * HH);
#pragma unroll
    for (int i = 0; i < 4; ++i) r4[i] = row[lane + 64 * i];
  }

  for (int s0 = 0; s0 < 256; s0 += 8) {
    float4 r4n[4] = {};
    if (s0 + 8 < 256) {
      const float4* row = (const float4*)(encb + (size_t)(base + s0 + 8 + wv) * HH);
#pragma unroll
      for (int i = 0; i < 4; ++i) r4n[i] = row[lane + 64 * i];
    }
    float p = 0.0f;
#pragma unroll
    for (int i = 0; i < 4; ++i)
      p += r4[i].x * er[i].x + r4[i].y * er[i].y + r4[i].z * er[i].z + r4[i].w * er[i].w;
#pragma unroll
    for (int off = 32; off; off >>= 1) p += __shfl_xor(p, off);
    if (lane == 0) { part[wv] = p; scb[(size_t)b * SS + base + s0 + wv] = p; }
    __syncthreads();

    float pv[8];
    float mx = m;
#pragma unroll
    for (int w = 0; w < 8; ++w) { pv[w] = part[w]; mx = fmaxf(mx, pv[w]); }
    const float alpha = expf(m - mx);
    float esum = 0.0f;
    float2 add = {0.0f, 0.0f};
#pragma unroll
    for (int w = 0; w < 8; ++w) {
      const float e = expf(pv[w] - mx);
      esum += e;
      const float2 v = ((const float2*)(encb + (size_t)(base + s0 + w) * HH))[t];
      add.x += e * v.x; add.y += e * v.y;
    }
    l = l * alpha + esum;
    cacc.x = cacc.x * alpha + add.x;
    cacc.y = cacc.y * alpha + add.y;
    m = mx;
    __syncthreads();
#pragma unroll
    for (int i = 0; i < 4; ++i) r4[i] = r4n[i];
  }

  if (t == 0) { pml[(b * 2 + half) * 2 + 0] = m; pml[(b * 2 + half) * 2 + 1] = l; }
  ((float2*)(pcacc + ((size_t)b * 2 + half) * HH))[t] = cacc;
}

// Merge the two halves: context -> hcat[:,1024:], weights -> wout.
__global__ __launch_bounds__(512) void attn_merge(
    const float* __restrict__ pml, const float* __restrict__ pcacc,
    const float* __restrict__ scb,
    __bf16* __restrict__ hcat_h, __bf16* __restrict__ hcat_l,
    float* __restrict__ wout)
{
  const int b = blockIdx.x, t = threadIdx.x;
  const float m0 = pml[b * 4 + 0], l0 = pml[b * 4 + 1];
  const float m1 = pml[b * 4 + 2], l1 = pml[b * 4 + 3];
  const float M = fmaxf(m0, m1);
  const float w0 = expf(m0 - M), w1 = expf(m1 - M);
  const float inv = 1.0f / (l0 * w0 + l1 * w1);
  const float2 c0 = ((const float2*)(pcacc + (size_t)b * 2048))[t];
  const float2 c1 = ((const float2*)(pcacc + (size_t)b * 2048 + 1024))[t];
  const float ox = (c0.x * w0 + c1.x * w1) * inv;
  const float oy = (c0.y * w0 + c1.y * w1) * inv;
  __bf16 h0, lo0, h1, lo1;
  split1(ox, h0, lo0); split1(oy, h1, lo1);
  const size_t ob = (size_t)b * 2048 + 1024 + 2 * t;
  *(bf16x2*)&hcat_h[ob] = bf16x2{h0, h1};
  *(bf16x2*)&hcat_l[ob] = bf16x2{lo0, lo1};
  wout[(size_t)b * SS + t] = expf(scb[(size_t)b * SS + t] - M) * inv;
}

// ---------------------------------------------------------------------------
// Greedy argmax over V=2048 logits; first-index tie-break.
// ---------------------------------------------------------------------------
__global__ __launch_bounds__(256) void argmax_kernel(
    const float* __restrict__ logits, int ldl, int coff, int* __restrict__ inp)
{
  const int b = blockIdx.x, t = threadIdx.x;
  const float* row = logits + (size_t)b * ldl + coff;
  float best = -INFINITY; int bi = 0;
  for (int j = t; j < VV; j += 256) {
    const float v = row[j];
    if (v > best) { best = v; bi = j; }
  }
  __shared__ float vs[256];
  __shared__ int   is[256];
  vs[t] = best; is[t] = bi;
  __syncthreads();
  for (int stp = 128; stp; stp >>= 1) {
    if (t < stp) {
      const float v2 = vs[t + stp]; const int i2 = is[t + stp];
      if (v2 > vs[t] || (v2 == vs[t] && i2 < is[t])) { vs[t] = v2; is[t] = i2; }
    }
    __syncthreads();
  }
  if (t == 0) inp[b] = is[0];
}

// ---------------------------------------------------------------------------
// Init: h,c <- h0,c0 ; h split into hcat[:,0:1024]; combined bias; SOS inp.
// ---------------------------------------------------------------------------
__global__ __launch_bounds__(256) void init_kernel(
    const float* __restrict__ h0, const float* __restrict__ c0,
    float* h, float* c,
    const float* __restrict__ b_ih, const float* __restrict__ b_hh,
    float* bihh, int* inp,
    __bf16* __restrict__ hcat_h, __bf16* __restrict__ hcat_l)
{
  const int id = blockIdx.x * 256 + threadIdx.x;
  if (id < BB * HH) {
    const float hv = h0[id];
    h[id] = hv;
    c[id] = c0[id];
    __bf16 hh, hl;
    split1(hv, hh, hl);
    const int b = id >> 10, j = id & 1023;
    hcat_h[(size_t)b * 2048 + j] = hh;
    hcat_l[(size_t)b * 2048 + j] = hl;
  }
  if (id < 4096) bihh[id] = b_ih[id] + b_hh[id];
  if (id < BB) inp[id] = SOS;
}

extern "C" void kernel_launch(void* const* d_in, const int* in_sizes, int n_in,
                              void* d_out, int out_size, void* d_ws, size_t ws_size,
                              hipStream_t stream)
{
  (void)in_sizes; (void)n_in; (void)out_size; (void)ws_size;
  const float* enc      = (const float*)d_in[0];
  const float* h0       = (const float*)d_in[1];
  const float* c0       = (const float*)d_in[2];
  const float* emb      = (const float*)d_in[3];
  const float* W_ih     = (const float*)d_in[4];
  const float* W_hh     = (const float*)d_in[5];
  const float* b_ih     = (const float*)d_in[6];
  const float* b_hh     = (const float*)d_in[7];
  const float* attn_W   = (const float*)d_in[8];
  const float* attn_b   = (const float*)d_in[9];
  const float* concat_W = (const float*)d_in[10];
  const float* concat_b = (const float*)d_in[11];
  const float* lin_W    = (const float*)d_in[12];
  const float* lin_b    = (const float*)d_in[13];

  float* out = (float*)d_out;
  float* dec = out;                                  // [256][6][2048]
  float* h   = out + (size_t)BB * NSTEPS * VV;       // [256][1024]
  float* c   = h + (size_t)BB * HH;                  // [256][1024]
  float* wts = c + (size_t)BB * HH;                  // [256][512]

  char* w = (char*)d_ws;
  auto alloc = [&](size_t bytes) { char* p = w; w += (bytes + 255) & ~255ull; return p; };
  float*  gates   = (float*)alloc((size_t)BB * 4096 * 4);
  float*  energy  = (float*)alloc((size_t)BB * HH * 4);
  float*  bihh    = (float*)alloc(4096 * 4);
  int*    inp     = (int*)alloc(BB * 4);
  __bf16* Wcat_h  = (__bf16*)alloc((size_t)4096 * 2048 * 2);
  __bf16* Wcat_l  = (__bf16*)alloc((size_t)4096 * 2048 * 2);
  __bf16* attnW_h = (__bf16*)alloc((size_t)1024 * 1024 * 2);
  __bf16* attnW_l = (__bf16*)alloc((size_t)1024 * 1024 * 2);
  __bf16* catW_h  = (__bf16*)alloc((size_t)1024 * 2048 * 2);
  __bf16* catW_l  = (__bf16*)alloc((size_t)1024 * 2048 * 2);
  __bf16* linW_h  = (__bf16*)alloc((size_t)2048 * 1024 * 2);
  __bf16* linW_l  = (__bf16*)alloc((size_t)2048 * 1024 * 2);
  __bf16* emb_h   = (__bf16*)alloc((size_t)VV * HH * 2);
  __bf16* emb_l   = (__bf16*)alloc((size_t)VV * HH * 2);
  __bf16* hcat_h  = (__bf16*)alloc((size_t)BB * 2048 * 2);
  __bf16* hcat_l  = (__bf16*)alloc((size_t)BB * 2048 * 2);
  __bf16* co_h    = (__bf16*)alloc((size_t)BB * 1024 * 2);
  __bf16* co_l    = (__bf16*)alloc((size_t)BB * 1024 * 2);
  float*  pml     = (float*)alloc(BB * 4 * 4);
  float*  pcacc   = (float*)alloc((size_t)BB * 2 * HH * 4);
  float*  scb     = (float*)alloc((size_t)BB * SS * 4);

  conv_all<<<15360, 256, 0, stream>>>(W_ih, W_hh, attn_W, concat_W, lin_W, emb,
                                      Wcat_h, Wcat_l, attnW_h, attnW_l,
                                      catW_h, catW_l, linW_h, linW_l, emb_h, emb_l);
  init_kernel<<<1024, 256, 0, stream>>>(h0, c0, h, c, b_ih, b_hh, bihh, inp,
                                        hcat_h, hcat_l);

  for (int step = 0; step < NSTEPS; ++step) {
    // gates = [emb[inp] | h] @ [W_ih|W_hh]^T + bihh   [256][4096]
    gemm3<0, 0, 1><<<dim3(64, 4), 256, 0, stream>>>(
        emb_h, emb_l, HH, hcat_h, hcat_l, inp, Wcat_h, Wcat_l, bihh, 2048,
        gates, 4096, 0, nullptr, nullptr, 0);
    lstm_kernel<<<1024, 256, 0, stream>>>(gates, c, h, hcat_h, hcat_l);
    // energy = h @ attn_W^T + attn_b   [256][1024]
    gemm3<0, 0, 0><<<dim3(16, 4), 256, 0, stream>>>(
        hcat_h, hcat_l, 2048, nullptr, nullptr, nullptr, attnW_h, attnW_l,
        attn_b, 1024, energy, 1024, 0, nullptr, nullptr, 0);
    // fused scores/softmax/context, S split in two for occupancy
    attn_part<<<2 * BB, 512, 0, stream>>>(energy, enc, pml, pcacc, scb);
    attn_merge<<<BB, 512, 0, stream>>>(pml, pcacc, scb, hcat_h, hcat_l, wts);
    // co = tanh([h|ctx] @ concat_W^T + concat_b) -> split
    gemm3<1, 1, 0><<<dim3(16, 4), 256, 0, stream>>>(
        hcat_h, hcat_l, 2048, nullptr, nullptr, nullptr, catW_h, catW_l,
        concat_b, 2048, nullptr, 0, 0, co_h, co_l, 1024);
    // logits = co @ lin_W^T + lin_b -> d_out[:, step, :]
    gemm3<0, 0, 0><<<dim3(32, 4), 256, 0, stream>>>(
        co_h, co_l, 1024, nullptr, nullptr, nullptr, linW_h, linW_l,
        lin_b, 1024, dec, NSTEPS * VV, step * VV, nullptr, nullptr, 0);
    argmax_kernel<<<BB, 256, 0, stream>>>(dec, NSTEPS * VV, step * VV, inp);
  }
}

// Round 5
// 879.267 us; speedup vs baseline: 4.0064x; 1.8031x over previous
//
#include <hip/hip_runtime.h>
#include <math.h>

#define HH 1024
#define VV 2048
#define BB 256
#define SS 512
#define NSTEPS 6
#define SOS 129

typedef __attribute__((ext_vector_type(8))) __bf16 bf16x8;
typedef __attribute__((ext_vector_type(4))) __bf16 bf16x4;
typedef __attribute__((ext_vector_type(2))) __bf16 bf16x2;
typedef __attribute__((ext_vector_type(4))) float f32x4;

__device__ __forceinline__ float sigmoidf_(float x) { return 1.0f / (1.0f + expf(-x)); }

__device__ __forceinline__ void split1(float x, __bf16& h, __bf16& l) {
  h = (__bf16)x;
  l = (__bf16)(x - (float)h);
}

// async global->LDS, 16B per lane; LDS dest must be wave-uniform base.
__device__ __forceinline__ void gll16(const __bf16* src, __bf16* ldst) {
  __builtin_amdgcn_global_load_lds(
      (const __attribute__((address_space(1))) unsigned*)(const void*)src,
      (__attribute__((address_space(3))) unsigned*)(void*)ldst, 16, 0, 0);
}

// ---------------------------------------------------------------------------
// Split-bf16 MFMA GEMM, double-buffered, global_load_lds staging, SPLIT-K.
// P[z][m][n] = sum_{k in chunk z} A[m][k]*B[n][k]   (raw fp32 partials,
// bias/activation applied by the consuming reduce kernel).
// Tile 64x64, BK=64, 256 threads (4 waves), wave-tile 32x32, chunk = kLen.
// AMODE 0: A = Ah/Al, row stride lda.
// AMODE 1: A = [emb[aidx[r]] | hcat[r][0:1024]] (gates GEMM, K=2048).
// ---------------------------------------------------------------------------
template<int AMODE>
__global__ __launch_bounds__(256) void gemm3(
    const __bf16* __restrict__ Ah, const __bf16* __restrict__ Al, int lda,
    const __bf16* __restrict__ A1h, const __bf16* __restrict__ A1l,
    const int* __restrict__ aidx,
    const __bf16* __restrict__ Bh, const __bf16* __restrict__ Bl, int K,
    int kLen, float* __restrict__ P, int ldc)
{
  __shared__ __align__(16) __bf16 lds[2][4][64 * 64];  // 64 KB
  const int t = threadIdx.x, lane = t & 63, wv = t >> 6;
  const int row0 = blockIdx.y * 64, col0 = blockIdx.x * 64;

  const int sslot = lane & 7;
  const int srw   = lane >> 3;
  int sw[2];
  const __bf16 *arh[2], *arl[2], *a1h[2], *a1l[2], *brh[2], *brl[2];
#pragma unroll
  for (int hf = 0; hf < 2; ++hf) {
    const int tr = wv * 16 + hf * 8 + srw;
    sw[hf] = (sslot ^ (tr & 7)) << 3;
    const int ar = row0 + tr;
    if (AMODE == 1) {
      const int r = aidx[ar];
      arh[hf] = Ah + (size_t)r * HH;
      arl[hf] = Al + (size_t)r * HH;
      a1h[hf] = A1h + (size_t)ar * 2048;
      a1l[hf] = A1l + (size_t)ar * 2048;
    } else {
      arh[hf] = Ah + (size_t)ar * lda;
      arl[hf] = Al + (size_t)ar * lda;
    }
    const int br = col0 + tr;
    brh[hf] = Bh + (size_t)br * K;
    brl[hf] = Bl + (size_t)br * K;
  }

  const int wr = (wv >> 1) * 32, wc = (wv & 1) * 32;
  const int fr = lane & 15, kb = (lane >> 4) * 8;

  const f32x4 fz = {0.f, 0.f, 0.f, 0.f};
  f32x4 acc[2][2] = {{fz, fz}, {fz, fz}};

  const int tBeg = (blockIdx.z * kLen) >> 6;
  const int nt = kLen >> 6;

  auto stage = [&](int tIdx, int bi) {
    const int k0 = tIdx << 6;
#pragma unroll
    for (int hf = 0; hf < 2; ++hf) {
      const int rb = (wv * 16 + hf * 8) * 64;
      const __bf16 *sa_h, *sa_l;
      if (AMODE == 1 && k0 >= HH) {
        sa_h = a1h[hf] + (k0 - HH) + sw[hf];
        sa_l = a1l[hf] + (k0 - HH) + sw[hf];
      } else {
        sa_h = arh[hf] + k0 + sw[hf];
        sa_l = arl[hf] + k0 + sw[hf];
      }
      gll16(sa_h, &lds[bi][0][rb]);
      gll16(sa_l, &lds[bi][1][rb]);
      gll16(brh[hf] + k0 + sw[hf], &lds[bi][2][rb]);
      gll16(brl[hf] + k0 + sw[hf], &lds[bi][3][rb]);
    }
  };

  auto compute = [&](int bi) {
#pragma unroll
    for (int kc = 0; kc < 2; ++kc) {
      const int e = kc * 32 + kb;
      bf16x8 a_h[2], a_l[2], b_h[2], b_l[2];
#pragma unroll
      for (int i = 0; i < 2; ++i) {
        const int ra = wr + i * 16 + fr;
        const int ia = ra * 64 + (e ^ ((ra & 7) << 3));
        a_h[i] = *(const bf16x8*)&lds[bi][0][ia];
        a_l[i] = *(const bf16x8*)&lds[bi][1][ia];
        const int rb2 = wc + i * 16 + fr;
        const int ib = rb2 * 64 + (e ^ ((rb2 & 7) << 3));
        b_h[i] = *(const bf16x8*)&lds[bi][2][ib];
        b_l[i] = *(const bf16x8*)&lds[bi][3][ib];
      }
#pragma unroll
      for (int i = 0; i < 2; ++i)
#pragma unroll
        for (int j = 0; j < 2; ++j)
          acc[i][j] = __builtin_amdgcn_mfma_f32_16x16x32_bf16(a_h[i], b_h[j], acc[i][j], 0, 0, 0);
#pragma unroll
      for (int i = 0; i < 2; ++i)
#pragma unroll
        for (int j = 0; j < 2; ++j)
          acc[i][j] = __builtin_amdgcn_mfma_f32_16x16x32_bf16(a_h[i], b_l[j], acc[i][j], 0, 0, 0);
#pragma unroll
      for (int i = 0; i < 2; ++i)
#pragma unroll
        for (int j = 0; j < 2; ++j)
          acc[i][j] = __builtin_amdgcn_mfma_f32_16x16x32_bf16(a_l[i], b_h[j], acc[i][j], 0, 0, 0);
    }
  };

  stage(tBeg, 0);
  __syncthreads();
  int cur = 0;
  for (int tk = 0; tk < nt; ++tk) {
    if (tk + 1 < nt) stage(tBeg + tk + 1, cur ^ 1);
    compute(cur);
    __syncthreads();
    cur ^= 1;
  }

  float* Cp = P + (size_t)blockIdx.z * 256 * ldc;
#pragma unroll
  for (int i = 0; i < 2; ++i)
#pragma unroll
    for (int j = 0; j < 2; ++j) {
      const int col = col0 + wc + j * 16 + fr;
#pragma unroll
      for (int r = 0; r < 4; ++r) {
        const int row = row0 + wr + i * 16 + (lane >> 4) * 4 + r;
        Cp[(size_t)row * ldc + col] = acc[i][j][r];
      }
    }
}

// ---------------------------------------------------------------------------
// One-shot conversion of all fp32 weights (+ embedding) to split hi/lo bf16.
// ---------------------------------------------------------------------------
__global__ __launch_bounds__(256) void conv_all(
    const float* __restrict__ W_ih, const float* __restrict__ W_hh,
    const float* __restrict__ attn_W, const float* __restrict__ concat_W,
    const float* __restrict__ lin_W, const float* __restrict__ emb,
    __bf16* __restrict__ Wcat_h, __bf16* __restrict__ Wcat_l,
    __bf16* __restrict__ attnW_h, __bf16* __restrict__ attnW_l,
    __bf16* __restrict__ catW_h, __bf16* __restrict__ catW_l,
    __bf16* __restrict__ linW_h, __bf16* __restrict__ linW_l,
    __bf16* __restrict__ emb_h, __bf16* __restrict__ emb_l)
{
  const int i = blockIdx.x * 256 + threadIdx.x;
  const float* s;
  __bf16 *dh, *dl;
  size_t so, dofs;
  if (i < 2097152) {
    const int ii = i & 1048575;
    const int r = ii >> 8, cp = (ii & 255) << 2;
    s = (i < 1048576) ? W_ih : W_hh;
    so = (size_t)r * 1024 + cp;
    dh = Wcat_h; dl = Wcat_l;
    dofs = (size_t)r * 2048 + ((i < 1048576) ? 0 : 1024) + cp;
  } else if (i < 2359296) {
    const size_t ii = (size_t)(i - 2097152) << 2;
    s = attn_W; so = ii; dh = attnW_h; dl = attnW_l; dofs = ii;
  } else if (i < 2883584) {
    const size_t ii = (size_t)(i - 2359296) << 2;
    s = concat_W; so = ii; dh = catW_h; dl = catW_l; dofs = ii;
  } else if (i < 3407872) {
    const size_t ii = (size_t)(i - 2883584) << 2;
    s = lin_W; so = ii; dh = linW_h; dl = linW_l; dofs = ii;
  } else {
    const size_t ii = (size_t)(i - 3407872) << 2;
    s = emb; so = ii; dh = emb_h; dl = emb_l; dofs = ii;
  }
  const float4 v = *(const float4*)(s + so);
  __bf16 h0, l0, h1, l1, h2, l2, h3, l3;
  split1(v.x, h0, l0); split1(v.y, h1, l1); split1(v.z, h2, l2); split1(v.w, h3, l3);
  *(bf16x4*)&dh[dofs] = bf16x4{h0, h1, h2, h3};
  *(bf16x4*)&dl[dofs] = bf16x4{l0, l1, l2, l3};
}

// ---------------------------------------------------------------------------
// gates reduce (2 split-K chunks) + bias + LSTM elementwise; emits h split.
// ---------------------------------------------------------------------------
__global__ __launch_bounds__(256) void lstm_reduce(
    const float* __restrict__ Pg, const float* __restrict__ bihh,
    float* c, float* h,
    __bf16* __restrict__ hcat_h, __bf16* __restrict__ hcat_l)
{
  const int id = blockIdx.x * 256 + threadIdx.x;  // 0..262143
  const int b = id >> 10, j = id & 1023;
  const size_t base = (size_t)b * 4096 + j;
  const size_t cs = (size_t)256 * 4096;
  const float ig = Pg[base]        + Pg[base + cs]        + bihh[j];
  const float fg = Pg[base + 1024] + Pg[base + cs + 1024] + bihh[j + 1024];
  const float gg = Pg[base + 2048] + Pg[base + cs + 2048] + bihh[j + 2048];
  const float og = Pg[base + 3072] + Pg[base + cs + 3072] + bihh[j + 3072];
  const float cn = sigmoidf_(fg) * c[id] + sigmoidf_(ig) * tanhf(gg);
  const float hn = sigmoidf_(og) * tanhf(cn);
  c[id] = cn;
  h[id] = hn;
  __bf16 hh, hl;
  split1(hn, hh, hl);
  hcat_h[(size_t)b * 2048 + j] = hh;
  hcat_l[(size_t)b * 2048 + j] = hl;
}

// ---------------------------------------------------------------------------
// Single-pass attention. WG (b, half) covers 256 enc rows; each of the 8
// waves is an INDEPENDENT online-softmax unit over its own 32 rows:
// score from register-resident row, then ctx += e*row into a private LDS
// slice (no barriers in the loop). Energy = sum of 4 split-K partials + bias
// (fused reduce). Defer-max (THR=8) keeps rescales rare. 8-way exact merge
// at the end -> per-(b,half) (m,l,ctx).
// ---------------------------------------------------------------------------
__global__ __launch_bounds__(512) void attn_part(
    const float* __restrict__ Pe, const float* __restrict__ attn_b,
    const float* __restrict__ enc,
    float* __restrict__ pml, float* __restrict__ pcacc, float* __restrict__ scb)
{
  const int b = blockIdx.x >> 1, half = blockIdx.x & 1;
  const int base = half * 256;
  const int t = threadIdx.x, lane = t & 63, wv = t >> 6;
  __shared__ __align__(16) float ctxa[8][1024];  // 32 KB, one slice per wave
  __shared__ float wml[8][2];
  const float* encb = enc + (size_t)b * (SS * HH);

  // energy reduce: er = sum of 4 chunks + attn_b
  f32x4 er[4];
  {
    const f32x4* P4 = (const f32x4*)Pe;
    const f32x4* B4 = (const f32x4*)attn_b;
#pragma unroll
    for (int i = 0; i < 4; ++i) {
      const size_t idx = (size_t)b * 256 + lane + 64 * i;
      f32x4 v = P4[idx];
      const f32x4 v1 = P4[idx + 65536], v2 = P4[idx + 131072], v3 = P4[idx + 196608];
      const f32x4 bb = B4[lane + 64 * i];
      v.x += v1.x + v2.x + v3.x + bb.x; v.y += v1.y + v2.y + v3.y + bb.y;
      v.z += v1.z + v2.z + v3.z + bb.z; v.w += v1.w + v2.w + v3.w + bb.w;
      er[i] = v;
    }
  }

  // zero this wave's ctx slice
  f32x4* cx = (f32x4*)ctxa[wv];
#pragma unroll
  for (int i = 0; i < 4; ++i) cx[lane + 64 * i] = f32x4{0.f, 0.f, 0.f, 0.f};

  float m = -INFINITY, lw = 0.0f;
  const int r0 = base + wv * 32;  // this wave's 32 rows

  f32x4 r4[4];
  {
    const f32x4* row = (const f32x4*)(encb + (size_t)r0 * HH);
#pragma unroll
    for (int i = 0; i < 4; ++i) r4[i] = __builtin_nontemporal_load(&row[lane + 64 * i]);
  }

  for (int s = 0; s < 32; ++s) {
    f32x4 r4n[4];
    if (s + 1 < 32) {
      const f32x4* row = (const f32x4*)(encb + (size_t)(r0 + s + 1) * HH);
#pragma unroll
      for (int i = 0; i < 4; ++i) r4n[i] = __builtin_nontemporal_load(&row[lane + 64 * i]);
    }
    float p = 0.0f;
#pragma unroll
    for (int i = 0; i < 4; ++i)
      p += r4[i].x * er[i].x + r4[i].y * er[i].y + r4[i].z * er[i].z + r4[i].w * er[i].w;
#pragma unroll
    for (int off = 32; off; off >>= 1) p += __shfl_xor(p, off);
    if (lane == 0) scb[(size_t)b * SS + r0 + s] = p;

    if (p > m + 8.0f) {  // defer-max rescale (wave-uniform; exact algebra)
      const float alpha = expf(m - p);  // first iter: exp(-inf)=0, ctx already 0
      lw *= alpha;
#pragma unroll
      for (int i = 0; i < 4; ++i) {
        f32x4 v = cx[lane + 64 * i];
        v.x *= alpha; v.y *= alpha; v.z *= alpha; v.w *= alpha;
        cx[lane + 64 * i] = v;
      }
      m = p;
    }
    const float e = expf(p - m);
    lw += e;
#pragma unroll
    for (int i = 0; i < 4; ++i) {
      f32x4 v = cx[lane + 64 * i];
      v.x += e * r4[i].x; v.y += e * r4[i].y; v.z += e * r4[i].z; v.w += e * r4[i].w;
      cx[lane + 64 * i] = v;
    }
#pragma unroll
    for (int i = 0; i < 4; ++i) r4[i] = r4n[i];
  }

  if (lane == 0) { wml[wv][0] = m; wml[wv][1] = lw; }
  __syncthreads();

  // 8-way merge (all threads)
  float M = -INFINITY;
#pragma unroll
  for (int w = 0; w < 8; ++w) M = fmaxf(M, wml[w][0]);
  float ew[8];
  float L = 0.0f;
#pragma unroll
  for (int w = 0; w < 8; ++w) { ew[w] = expf(wml[w][0] - M); L += wml[w][1] * ew[w]; }

  float2 acc = {0.0f, 0.0f};
#pragma unroll
  for (int w = 0; w < 8; ++w) {
    const float2 v = ((const float2*)ctxa[w])[t];
    acc.x += ew[w] * v.x; acc.y += ew[w] * v.y;
  }
  ((float2*)(pcacc + ((size_t)b * 2 + half) * HH))[t] = acc;
  if (t == 0) { pml[(b * 2 + half) * 2 + 0] = M; pml[(b * 2 + half) * 2 + 1] = L; }
}

// Merge the two halves: context -> hcat[:,1024:], weights -> wout.
__global__ __launch_bounds__(512) void attn_merge(
    const float* __restrict__ pml, const float* __restrict__ pcacc,
    const float* __restrict__ scb,
    __bf16* __restrict__ hcat_h, __bf16* __restrict__ hcat_l,
    float* __restrict__ wout)
{
  const int b = blockIdx.x, t = threadIdx.x;
  const float m0 = pml[b * 4 + 0], l0 = pml[b * 4 + 1];
  const float m1 = pml[b * 4 + 2], l1 = pml[b * 4 + 3];
  const float M = fmaxf(m0, m1);
  const float w0 = expf(m0 - M), w1 = expf(m1 - M);
  const float inv = 1.0f / (l0 * w0 + l1 * w1);
  const float2 c0 = ((const float2*)(pcacc + (size_t)b * 2048))[t];
  const float2 c1 = ((const float2*)(pcacc + (size_t)b * 2048 + 1024))[t];
  const float ox = (c0.x * w0 + c1.x * w1) * inv;
  const float oy = (c0.y * w0 + c1.y * w1) * inv;
  __bf16 h0, lo0, h1, lo1;
  split1(ox, h0, lo0); split1(oy, h1, lo1);
  const size_t ob = (size_t)b * 2048 + 1024 + 2 * t;
  *(bf16x2*)&hcat_h[ob] = bf16x2{h0, h1};
  *(bf16x2*)&hcat_l[ob] = bf16x2{lo0, lo1};
  wout[(size_t)b * SS + t] = expf(scb[(size_t)b * SS + t] - M) * inv;
}

// ---------------------------------------------------------------------------
// co reduce (4 chunks) + bias + tanh + split -> co_h/co_l.
// ---------------------------------------------------------------------------
__global__ __launch_bounds__(256) void co_reduce(
    const float* __restrict__ Pc, const float* __restrict__ concat_b,
    __bf16* __restrict__ co_h, __bf16* __restrict__ co_l)
{
  const int id = blockIdx.x * 256 + threadIdx.x;  // float4 group, 0..65535
  const size_t e4 = (size_t)id << 2;
  const int j = (int)(e4 & 1023);
  const size_t cs = (size_t)256 * 1024;
  float4 v = *(const float4*)(Pc + e4);
  const float4 v1 = *(const float4*)(Pc + e4 + cs);
  const float4 v2 = *(const float4*)(Pc + e4 + 2 * cs);
  const float4 v3 = *(const float4*)(Pc + e4 + 3 * cs);
  const float4 bb = *(const float4*)(concat_b + j);
  v.x = tanhf(v.x + v1.x + v2.x + v3.x + bb.x);
  v.y = tanhf(v.y + v1.y + v2.y + v3.y + bb.y);
  v.z = tanhf(v.z + v1.z + v2.z + v3.z + bb.z);
  v.w = tanhf(v.w + v1.w + v2.w + v3.w + bb.w);
  __bf16 h0, l0, h1, l1, h2, l2, h3, l3;
  split1(v.x, h0, l0); split1(v.y, h1, l1); split1(v.z, h2, l2); split1(v.w, h3, l3);
  *(bf16x4*)&co_h[e4] = bf16x4{h0, h1, h2, h3};
  *(bf16x4*)&co_l[e4] = bf16x4{l0, l1, l2, l3};
}

// ---------------------------------------------------------------------------
// logits reduce (2 chunks) + bias -> dec output, fused greedy argmax
// (first-index tie-break, deterministic).
// ---------------------------------------------------------------------------
__global__ __launch_bounds__(256) void argmax_reduce(
    const float* __restrict__ Pl, const float* __restrict__ lin_b,
    float* __restrict__ dec, int coff, int* __restrict__ inp)
{
  const int b = blockIdx.x, t = threadIdx.x;
  const size_t rb = (size_t)b * 2048;
  const size_t cs = (size_t)256 * 2048;
  float* drow = dec + (size_t)b * (NSTEPS * VV) + coff;
  float best = -INFINITY; int bi = 0;
  for (int j = t; j < VV; j += 256) {
    const float v = Pl[rb + j] + Pl[rb + cs + j] + lin_b[j];
    drow[j] = v;
    if (v > best) { best = v; bi = j; }
  }
  __shared__ float vs[256];
  __shared__ int   is[256];
  vs[t] = best; is[t] = bi;
  __syncthreads();
  for (int stp = 128; stp; stp >>= 1) {
    if (t < stp) {
      const float v2 = vs[t + stp]; const int i2 = is[t + stp];
      if (v2 > vs[t] || (v2 == vs[t] && i2 < is[t])) { vs[t] = v2; is[t] = i2; }
    }
    __syncthreads();
  }
  if (t == 0) inp[b] = is[0];
}

// ---------------------------------------------------------------------------
// Init: h,c <- h0,c0 ; h split into hcat[:,0:1024]; combined bias; SOS inp.
// ---------------------------------------------------------------------------
__global__ __launch_bounds__(256) void init_kernel(
    const float* __restrict__ h0, const float* __restrict__ c0,
    float* h, float* c,
    const float* __restrict__ b_ih, const float* __restrict__ b_hh,
    float* bihh, int* inp,
    __bf16* __restrict__ hcat_h, __bf16* __restrict__ hcat_l)
{
  const int id = blockIdx.x * 256 + threadIdx.x;
  if (id < BB * HH) {
    const float hv = h0[id];
    h[id] = hv;
    c[id] = c0[id];
    __bf16 hh, hl;
    split1(hv, hh, hl);
    const int b = id >> 10, j = id & 1023;
    hcat_h[(size_t)b * 2048 + j] = hh;
    hcat_l[(size_t)b * 2048 + j] = hl;
  }
  if (id < 4096) bihh[id] = b_ih[id] + b_hh[id];
  if (id < BB) inp[id] = SOS;
}

extern "C" void kernel_launch(void* const* d_in, const int* in_sizes, int n_in,
                              void* d_out, int out_size, void* d_ws, size_t ws_size,
                              hipStream_t stream)
{
  (void)in_sizes; (void)n_in; (void)out_size; (void)ws_size;
  const float* enc      = (const float*)d_in[0];
  const float* h0       = (const float*)d_in[1];
  const float* c0       = (const float*)d_in[2];
  const float* emb      = (const float*)d_in[3];
  const float* W_ih     = (const float*)d_in[4];
  const float* W_hh     = (const float*)d_in[5];
  const float* b_ih     = (const float*)d_in[6];
  const float* b_hh     = (const float*)d_in[7];
  const float* attn_W   = (const float*)d_in[8];
  const float* attn_b   = (const float*)d_in[9];
  const float* concat_W = (const float*)d_in[10];
  const float* concat_b = (const float*)d_in[11];
  const float* lin_W    = (const float*)d_in[12];
  const float* lin_b    = (const float*)d_in[13];

  float* out = (float*)d_out;
  float* dec = out;                                  // [256][6][2048]
  float* h   = out + (size_t)BB * NSTEPS * VV;       // [256][1024]
  float* c   = h + (size_t)BB * HH;                  // [256][1024]
  float* wts = c + (size_t)BB * HH;                  // [256][512]

  char* w = (char*)d_ws;
  auto alloc = [&](size_t bytes) { char* p = w; w += (bytes + 255) & ~255ull; return p; };
  float*  bihh    = (float*)alloc(4096 * 4);
  int*    inp     = (int*)alloc(BB * 4);
  __bf16* Wcat_h  = (__bf16*)alloc((size_t)4096 * 2048 * 2);
  __bf16* Wcat_l  = (__bf16*)alloc((size_t)4096 * 2048 * 2);
  __bf16* attnW_h = (__bf16*)alloc((size_t)1024 * 1024 * 2);
  __bf16* attnW_l = (__bf16*)alloc((size_t)1024 * 1024 * 2);
  __bf16* catW_h  = (__bf16*)alloc((size_t)1024 * 2048 * 2);
  __bf16* catW_l  = (__bf16*)alloc((size_t)1024 * 2048 * 2);
  __bf16* linW_h  = (__bf16*)alloc((size_t)2048 * 1024 * 2);
  __bf16* linW_l  = (__bf16*)alloc((size_t)2048 * 1024 * 2);
  __bf16* emb_h   = (__bf16*)alloc((size_t)VV * HH * 2);
  __bf16* emb_l   = (__bf16*)alloc((size_t)VV * HH * 2);
  __bf16* hcat_h  = (__bf16*)alloc((size_t)BB * 2048 * 2);
  __bf16* hcat_l  = (__bf16*)alloc((size_t)BB * 2048 * 2);
  __bf16* co_h    = (__bf16*)alloc((size_t)BB * 1024 * 2);
  __bf16* co_l    = (__bf16*)alloc((size_t)BB * 1024 * 2);
  float*  pml     = (float*)alloc(BB * 4 * 4);
  float*  pcacc   = (float*)alloc((size_t)BB * 2 * HH * 4);
  float*  scb     = (float*)alloc((size_t)BB * SS * 4);
  float*  Pg      = (float*)alloc((size_t)2 * BB * 4096 * 4);  // gates partials
  float*  Pe      = (float*)alloc((size_t)4 * BB * 1024 * 4);  // energy partials
  float*  Pc      = (float*)alloc((size_t)4 * BB * 1024 * 4);  // concat partials
  float*  Pl      = (float*)alloc((size_t)2 * BB * 2048 * 4);  // logits partials

  conv_all<<<15360, 256, 0, stream>>>(W_ih, W_hh, attn_W, concat_W, lin_W, emb,
                                      Wcat_h, Wcat_l, attnW_h, attnW_l,
                                      catW_h, catW_l, linW_h, linW_l, emb_h, emb_l);
  init_kernel<<<1024, 256, 0, stream>>>(h0, c0, h, c, b_ih, b_hh, bihh, inp,
                                        hcat_h, hcat_l);

  for (int step = 0; step < NSTEPS; ++step) {
    // gates partials: [emb[inp]|h] @ Wcat^T, split-K2 (1024 each)
    gemm3<1><<<dim3(64, 4, 2), 256, 0, stream>>>(
        emb_h, emb_l, HH, hcat_h, hcat_l, inp, Wcat_h, Wcat_l, 2048,
        1024, Pg, 4096);
    lstm_reduce<<<1024, 256, 0, stream>>>(Pg, bihh, c, h, hcat_h, hcat_l);
    // energy partials: h @ attn_W^T, split-K4 (256 each)
    gemm3<0><<<dim3(16, 4, 4), 256, 0, stream>>>(
        hcat_h, hcat_l, 2048, nullptr, nullptr, nullptr, attnW_h, attnW_l, 1024,
        256, Pe, 1024);
    // fused energy-reduce + single-pass flash attention
    attn_part<<<2 * BB, 512, 0, stream>>>(Pe, attn_b, enc, pml, pcacc, scb);
    attn_merge<<<BB, 512, 0, stream>>>(pml, pcacc, scb, hcat_h, hcat_l, wts);
    // concat partials: [h|ctx] @ concat_W^T, split-K4 (512 each)
    gemm3<0><<<dim3(16, 4, 4), 256, 0, stream>>>(
        hcat_h, hcat_l, 2048, nullptr, nullptr, nullptr, catW_h, catW_l, 2048,
        512, Pc, 1024);
    co_reduce<<<256, 256, 0, stream>>>(Pc, concat_b, co_h, co_l);
    // logits partials: co @ lin_W^T, split-K2 (512 each)
    gemm3<0><<<dim3(32, 4, 2), 256, 0, stream>>>(
        co_h, co_l, 1024, nullptr, nullptr, nullptr, linW_h, linW_l, 1024,
        512, Pl, 2048);
    argmax_reduce<<<BB, 256, 0, stream>>>(Pl, lin_b, dec, step * VV, inp);
  }
}